// Round 21
// baseline (298.308 us; speedup 1.0000x reference)
//
#include <hip/hip_runtime.h>

#define N_PTS   200000
#define N_EDGES 1600000
#define MEM_SIZE (1 << 27)

#define NP    10                              // node parts (LDS pushed to hw max)
#define NPB   20000                           // nodes/part; mn1+mn2 = 160,000 B LDS
#define EP    16                              // edge slices; W = 25.6 MB (proven)
#define EPS   (N_EDGES / EP)                  // 100000 edges per slice
#define EPS4  (EPS / 2)                       // 50000 int4 (2 edges) per slice
#define NSCAN (NP * EP)                       // 160 scan blocks
#define NBLK  256                             // 1 block/CU
#define NTHR  1024
#define NF4   (MEM_SIZE / 4)                  // 33,554,432 float4
// copy split: 160 scan blocks x 113 iters + 96 copy blocks x 153 iters
//           = 1024*(160*113 + 96*153) = 33,554,432 exact, ~balanced in time
#define CIT_S 113
#define CIT_C 153
#define OFFC  (NSCAN * NTHR * CIT_S)          // start of copy-only region
#define SITER ((EPS4 + NTHR - 1) / NTHR)      // 49

__device__ __forceinline__ void upd2(unsigned* __restrict__ mn1, unsigned* __restrict__ mn2,
                                     int a, unsigned i) {
    if ((unsigned)a < NPB) {
        unsigned old = atomicMin(&mn1[a], i);
        unsigned c = (i < old) ? old : i;      // displaced value or losing insert
        atomicMin(&mn2[a], c);                 // c==0xFFFFFFFF is a value no-op
    }
}

__device__ __forceinline__ void proc(unsigned* __restrict__ mn1, unsigned* __restrict__ mn2,
                                     int lo, int4 p, int g /* global int4 index */) {
    // int4 g holds edges 2g (p.x,p.y) and 2g+1 (p.z,p.w)
    unsigned ia0 = (unsigned)(2 * g);
    unsigned ib0 = (unsigned)(2 * g + N_EDGES);
    upd2(mn1, mn2, p.x - lo, ia0);
    upd2(mn1, mn2, p.y - lo, ib0);
    upd2(mn1, mn2, p.z - lo, ia0 + 1u);
    upd2(mn1, mn2, p.w - lo, ib0 + 1u);
}

// r14 structure with scan-CU population shrunk 256->160 (NP=10 via 160KB LDS)
// and the freed 96 CUs absorbing copy work. Per-scan-block op count (the
// measured cost driver) is unchanged; scan blocks carry 27% less copy.
__global__ __launch_bounds__(NTHR) void fused_copy_scan(const float4* __restrict__ src,
                                                        float4* __restrict__ dst,
                                                        const int4* __restrict__ edges4,
                                                        unsigned long long* __restrict__ W) {
    __shared__ unsigned mn1[NPB];
    __shared__ unsigned mn2[NPB];

    int b = blockIdx.x;
    int t = threadIdx.x;

    if (b < NSCAN) {
        int ep = b & 15;                 // slice 0..15
        int np = b >> 4;                 // node part 0..9
        int lo = np * NPB;

        for (int j = t; j < NPB; j += NTHR) { mn1[j] = 0xFFFFFFFFu; mn2[j] = 0xFFFFFFFFu; }
        __syncthreads();

        int q0 = ep * EPS4;              // slice start, int4 units
        int cbase = b * (NTHR * CIT_S) + t;

        #pragma unroll 8
        for (int j = 0; j < CIT_S; ++j) {
            int ci = cbase + j * NTHR;
            float4 v = src[ci];
            int k = t + j * NTHR;
            bool have = (j < SITER) && (k < EPS4);
            int4 p;
            if (have) p = edges4[q0 + k];
            dst[ci] = v;
            if (have) proc(mn1, mn2, lo, p, q0 + k);
        }
        __syncthreads();

        for (int j = t; j < NPB; j += NTHR) {
            int n = lo + j;                  // NP*NPB = 200000 exactly: n < N_PTS always
            W[(size_t)ep * N_PTS + n] =
                ((unsigned long long)mn2[j] << 32) | (unsigned long long)mn1[j];
        }
    } else {
        // copy-only block: 153 iters of its contiguous region
        int cb = b - NSCAN;
        int cbase = OFFC + cb * (NTHR * CIT_C) + t;
        #pragma unroll 8
        for (int j = 0; j < CIT_C; ++j) {
            int ci = cbase + j * NTHR;
            dst[ci] = src[ci];
        }
    }
}

__device__ __forceinline__ int quant6(float d) {
    // match jnp: clip(round((d + 1)/2 * 63), 0, 63); jnp.round = half-to-even -> rintf
    float x = ((d + 1.0f) / 2.0f) * 63.0f;
    float r = rintf(x);
    r = fminf(fmaxf(r, 0.0f), 63.0f);
    return (int)r;
}

__global__ void finalize(const float* __restrict__ pts, const float* __restrict__ tex,
                         const int2* __restrict__ edges,
                         const unsigned long long* __restrict__ W,
                         float* __restrict__ out) {
    int n = blockIdx.x * blockDim.x + threadIdx.x;
    if (n >= N_PTS) return;

    // merge EP per-slice (m1,m2) pairs -> global two smallest (all indices distinct)
    unsigned int k1 = 0xFFFFFFFFu, k2 = 0xFFFFFFFFu;
    #pragma unroll
    for (int s = 0; s < EP; ++s) {
        unsigned long long pr = W[(size_t)s * N_PTS + n];
        unsigned int m1 = (unsigned int)(pr & 0xFFFFFFFFu);
        unsigned int m2 = (unsigned int)(pr >> 32);
        if (m1 < k1) { k2 = k1; k1 = m1; } else if (m1 < k2) { k2 = m1; }
        if (m2 < k2 && m2 > k1) { k2 = m2; }
    }

    float px = pts[2 * n], py = pts[2 * n + 1];
    int t = (tex[n] > 0.7f) ? 1 : 0;

    int v0x = 0, v0y = 0, t0 = 0, v1x = 0, v1y = 0, t1 = 0;

    if (k1 < 2u * N_EDGES) {
        int k = (int)k1;
        int2 e = edges[(k < N_EDGES) ? k : (k - N_EDGES)];
        int dst = (k < N_EDGES) ? e.y : e.x;
        v0x = quant6(pts[2 * dst] - px);
        v0y = quant6(pts[2 * dst + 1] - py);
        t0 = (tex[dst] > 0.7f) ? 1 : 0;
    }
    if (k2 < 2u * N_EDGES) {
        int k = (int)k2;
        int2 e = edges[(k < N_EDGES) ? k : (k - N_EDGES)];
        int dst = (k < N_EDGES) ? e.y : e.x;
        v1x = quant6(pts[2 * dst] - px);
        v1y = quant6(pts[2 * dst + 1] - py);
        t1 = (tex[dst] > 0.7f) ? 1 : 0;
    }

    // hash keeps only cols 0..4 (col4 masked to 3 bits); each rel-variant
    // appears 6 times in rel_all (2 builds x 3 identity-rolls / 3 swap-rolls).
    int h_id = t | (v0x << 6) | (v0y << 12) | (t0 << 18) | ((v1x & 7) << 24);
    int h_sw = t | (v1x << 6) | (v1y << 12) | (t1 << 18) | ((v0x & 7) << 24);

    atomicAdd(&out[h_id], 6.0f);
    atomicAdd(&out[h_sw], 6.0f);
}

extern "C" void kernel_launch(void* const* d_in, const int* in_sizes, int n_in,
                              void* d_out, int out_size, void* d_ws, size_t ws_size,
                              hipStream_t stream) {
    const float* pts   = (const float*)d_in[0];
    const float* tex   = (const float*)d_in[1];
    const int2*  edges = (const int2*)d_in[2];   // int64 in ref -> int32 on device
    const float* mem   = (const float*)d_in[3];
    float*       out   = (float*)d_out;

    unsigned long long* W = (unsigned long long*)d_ws;   // 16 * 200K * 8B = 25.6 MB

    fused_copy_scan<<<NBLK, NTHR, 0, stream>>>(
        (const float4*)mem, (float4*)out, (const int4*)edges, W);
    finalize<<<(N_PTS + 255) / 256, 256, 0, stream>>>(pts, tex, edges, W, out);
}

// Round 22
// 278.879 us; speedup vs baseline: 1.0697x; 1.0697x over previous
//
#include <hip/hip_runtime.h>

#define N_PTS   200000
#define N_EDGES 1600000
#define MEM_SIZE (1 << 27)

#define NP   16                               // node parts
#define NPB  12800                            // nodes/part; 102.4KB LDS -> 1 block/CU
#define EP   16                               // edge slices; W = 25.6 MB
#define EPS  (N_EDGES / EP)                   // 100000 edges per slice
#define NBLK (NP * EP)                        // 256 blocks = exactly 1 per CU
#define NTHR 1024                             // 16 waves/block
#define NF4  (MEM_SIZE / 4)                   // 33,554,432 float4
#define CSTRIDE (NBLK * NTHR)                 // 262,144 threads
#define CITER (NF4 / CSTRIDE)                 // 128 f4 iters per thread
#define SITP ((EPS + NTHR - 1) / NTHR)        // 98: one packed edge per thread/iter

// Pre-pass: pack each edge 8B -> 5B (both node ids < 2^18).
// P0 = e.x | (e.y<<18)  (u32: e.x 18b + low 14b of e.y); H = e.y >> 14 (u8).
// Cuts the NP-fold slice re-read traffic 205MB -> 128MB.
__global__ __launch_bounds__(1024) void pack_edges(const int2* __restrict__ edges,
                                                   unsigned* __restrict__ P0,
                                                   unsigned char* __restrict__ H) {
    int i = blockIdx.x * 1024 + threadIdx.x;
    if (i < N_EDGES) {
        int2 e = edges[i];
        P0[i] = (unsigned)e.x | ((unsigned)e.y << 18);
        H[i]  = (unsigned char)((unsigned)e.y >> 14);
    }
}

__device__ __forceinline__ void upd2(unsigned* __restrict__ mn1, unsigned* __restrict__ mn2,
                                     int a, unsigned i) {
    if ((unsigned)a < NPB) {
        unsigned old = atomicMin(&mn1[a], i);
        unsigned c = (i < old) ? old : i;      // displaced value or losing insert
        atomicMin(&mn2[a], c);                 // c==0xFFFFFFFF is a value no-op
    }
}

// r14's proven fused copy + LDS 2-min scan, with packed 5B edges. Same grid,
// LDS, upd2, and interleave; the ONLY changed variable is re-read bytes
// (traffic-model discriminator after r10/r13/r15/r17/r20 nulls).
__global__ __launch_bounds__(NTHR) void fused_copy_scan(const float4* __restrict__ src,
                                                        float4* __restrict__ dst,
                                                        const unsigned* __restrict__ P0,
                                                        const unsigned char* __restrict__ H,
                                                        unsigned long long* __restrict__ W) {
    __shared__ unsigned mn1[NPB];
    __shared__ unsigned mn2[NPB];

    int b  = blockIdx.x;
    int ep = b & 15;                 // slice
    int np = b >> 4;                 // node part 0..15
    int lo = np * NPB;
    int t  = threadIdx.x;

    for (int j = t; j < NPB; j += NTHR) { mn1[j] = 0xFFFFFFFFu; mn2[j] = 0xFFFFFFFFu; }
    __syncthreads();

    int e0 = ep * EPS;               // slice start, edge units
    int cbase = b * NTHR + t;        // copy index, stride CSTRIDE

    #pragma unroll 8
    for (int j = 0; j < CITER; ++j) {
        int ci = cbase + j * CSTRIDE;
        float4 v = src[ci];
        int k = t + j * NTHR;
        bool have = (j < SITP) && (k < EPS);
        unsigned p; unsigned char h;
        if (have) { p = P0[e0 + k]; h = H[e0 + k]; }
        dst[ci] = v;
        if (have) {
            int ex = (int)(p & 0x3FFFFu);
            int ey = (int)((p >> 18) | ((unsigned)h << 14));
            unsigned i = (unsigned)(e0 + k);
            upd2(mn1, mn2, ex - lo, i);                        // forward half-edge
            upd2(mn1, mn2, ey - lo, i + (unsigned)N_EDGES);    // reverse half-edge
        }
    }
    __syncthreads();

    for (int j = t; j < NPB; j += NTHR) {
        int n = lo + j;
        if (n < N_PTS)
            W[(size_t)ep * N_PTS + n] =
                ((unsigned long long)mn2[j] << 32) | (unsigned long long)mn1[j];
    }
}

__device__ __forceinline__ int quant6(float d) {
    // match jnp: clip(round((d + 1)/2 * 63), 0, 63); jnp.round = half-to-even -> rintf
    float x = ((d + 1.0f) / 2.0f) * 63.0f;
    float r = rintf(x);
    r = fminf(fmaxf(r, 0.0f), 63.0f);
    return (int)r;
}

__global__ void finalize(const float* __restrict__ pts, const float* __restrict__ tex,
                         const int2* __restrict__ edges,
                         const unsigned long long* __restrict__ W,
                         float* __restrict__ out) {
    int n = blockIdx.x * blockDim.x + threadIdx.x;
    if (n >= N_PTS) return;

    // merge EP per-slice (m1,m2) pairs -> global two smallest (all indices distinct)
    unsigned int k1 = 0xFFFFFFFFu, k2 = 0xFFFFFFFFu;
    #pragma unroll
    for (int s = 0; s < EP; ++s) {
        unsigned long long pr = W[(size_t)s * N_PTS + n];
        unsigned int m1 = (unsigned int)(pr & 0xFFFFFFFFu);
        unsigned int m2 = (unsigned int)(pr >> 32);
        if (m1 < k1) { k2 = k1; k1 = m1; } else if (m1 < k2) { k2 = m1; }
        if (m2 < k2 && m2 > k1) { k2 = m2; }
    }

    float px = pts[2 * n], py = pts[2 * n + 1];
    int t = (tex[n] > 0.7f) ? 1 : 0;

    int v0x = 0, v0y = 0, t0 = 0, v1x = 0, v1y = 0, t1 = 0;

    if (k1 < 2u * N_EDGES) {
        int k = (int)k1;
        int2 e = edges[(k < N_EDGES) ? k : (k - N_EDGES)];
        int dst = (k < N_EDGES) ? e.y : e.x;
        v0x = quant6(pts[2 * dst] - px);
        v0y = quant6(pts[2 * dst + 1] - py);
        t0 = (tex[dst] > 0.7f) ? 1 : 0;
    }
    if (k2 < 2u * N_EDGES) {
        int k = (int)k2;
        int2 e = edges[(k < N_EDGES) ? k : (k - N_EDGES)];
        int dst = (k < N_EDGES) ? e.y : e.x;
        v1x = quant6(pts[2 * dst] - px);
        v1y = quant6(pts[2 * dst + 1] - py);
        t1 = (tex[dst] > 0.7f) ? 1 : 0;
    }

    // hash keeps only cols 0..4 (col4 masked to 3 bits); each rel-variant
    // appears 6 times in rel_all (2 builds x 3 identity-rolls / 3 swap-rolls).
    int h_id = t | (v0x << 6) | (v0y << 12) | (t0 << 18) | ((v1x & 7) << 24);
    int h_sw = t | (v1x << 6) | (v1y << 12) | (t1 << 18) | ((v0x & 7) << 24);

    atomicAdd(&out[h_id], 6.0f);
    atomicAdd(&out[h_sw], 6.0f);
}

extern "C" void kernel_launch(void* const* d_in, const int* in_sizes, int n_in,
                              void* d_out, int out_size, void* d_ws, size_t ws_size,
                              hipStream_t stream) {
    const float* pts   = (const float*)d_in[0];
    const float* tex   = (const float*)d_in[1];
    const int2*  edges = (const int2*)d_in[2];   // int64 in ref -> int32 on device
    const float* mem   = (const float*)d_in[3];
    float*       out   = (float*)d_out;

    // ws layout: P0 (6.4MB) | H (1.6MB) | W (25.6MB)  -> 33.6MB total
    unsigned*           P0 = (unsigned*)d_ws;
    unsigned char*      H  = (unsigned char*)(P0 + N_EDGES);
    unsigned long long* W  = (unsigned long long*)((char*)d_ws + 8 * 1024 * 1024);

    pack_edges<<<(N_EDGES + 1023) / 1024, 1024, 0, stream>>>(edges, P0, H);
    fused_copy_scan<<<NBLK, NTHR, 0, stream>>>(
        (const float4*)mem, (float4*)out, P0, H, W);
    finalize<<<(N_PTS + 255) / 256, 256, 0, stream>>>(pts, tex, edges, W, out);
}